// Round 1
// baseline (103.107 us; speedup 1.0000x reference)
//
#include <hip/hip_runtime.h>

// MorphClassifier: out[i] = wrap8(trunc(max(|x[i,0]+b0|, |x[i,1]+b1|)))
// Memory-bound: 96 MiB traffic -> ~15 us floor at 6.3 TB/s.
// Each thread: 4 rows = 2x float4 load + 1x float4 store, grid-stride.

__global__ __launch_bounds__(256) void morph_kernel(
    const float4* __restrict__ x,      // B/2 float4 (each holds 2 rows)
    const float* __restrict__ biases,  // [2]
    float4* __restrict__ out,          // B/4 float4
    int n4)                            // out_size / 4
{
    const float b0 = biases[0];
    const float b1 = biases[1];
    const int stride = gridDim.x * blockDim.x;
    for (int i = blockIdx.x * blockDim.x + threadIdx.x; i < n4; i += stride) {
        const float4 p = x[2 * i];
        const float4 q = x[2 * i + 1];
        // rows: (p.x,p.y) (p.z,p.w) (q.x,q.y) (q.z,q.w)
        const float m0 = fmaxf(fabsf(p.x + b0), fabsf(p.y + b1));
        const float m1 = fmaxf(fabsf(p.z + b0), fabsf(p.w + b1));
        const float m2 = fmaxf(fabsf(q.x + b0), fabsf(q.y + b1));
        const float m3 = fmaxf(fabsf(q.z + b0), fabsf(q.w + b1));
        // mx >= 0 always, so (int) == trunc and +128 stays non-negative:
        // ((vi+128) % 256) - 128  ==  ((vi+128) & 255) - 128
        float4 r;
        r.x = (float)((((int)m0 + 128) & 255) - 128);
        r.y = (float)((((int)m1 + 128) & 255) - 128);
        r.z = (float)((((int)m2 + 128) & 255) - 128);
        r.w = (float)((((int)m3 + 128) & 255) - 128);
        out[i] = r;
    }
}

extern "C" void kernel_launch(void* const* d_in, const int* in_sizes, int n_in,
                              void* d_out, int out_size, void* d_ws, size_t ws_size,
                              hipStream_t stream) {
    const float4* x      = (const float4*)d_in[0];   // [B,2] f32 -> B/2 float4
    const float*  biases = (const float*)d_in[1];    // [2]
    // d_in[2] (weights) and d_in[3] (threshold) are unused by the reference.
    float4* out = (float4*)d_out;

    const int n4 = out_size / 4;  // B = 8388608, divisible by 4
    const int block = 256;
    int grid = (n4 + block - 1) / block;
    if (grid > 2048) grid = 2048;  // grid-stride; 256 CU x 8 blocks/CU cap

    morph_kernel<<<grid, block, 0, stream>>>(x, biases, out, n4);
}

// Round 2
// 102.484 us; speedup vs baseline: 1.0061x; 1.0061x over previous
//
#include <hip/hip_runtime.h>

// MorphClassifier: out[i] = wrap8(trunc(max(|x[i,0]+b0|, |x[i,1]+b1|)))
// Memory-bound: 64 MiB in + 32 MiB out -> ~15 us floor at 6.3 TB/s.
//
// R2 fix vs R1: R1 had each thread load x4[2t] and x4[2t+1] -> 32B lane
// stride per load instruction (half the coalescing window wasted).
// Now each thread loads ONE contiguous float4 (16B/lane, ideal) = 2 rows,
// and stores one float2 (8B/lane, fully coalesced).

__global__ __launch_bounds__(256) void morph_kernel(
    const float4* __restrict__ x4,     // B/2 float4 (each = 2 rows of x[B,2])
    const float* __restrict__ biases,  // [2]
    float2* __restrict__ out2,         // B/2 float2
    int n)                             // B/2
{
    const float b0 = biases[0];
    const float b1 = biases[1];
    const int stride = gridDim.x * blockDim.x;
    for (int i = blockIdx.x * blockDim.x + threadIdx.x; i < n; i += stride) {
        const float4 p = x4[i];
        // rows: (p.x,p.y) and (p.z,p.w)
        const float m0 = fmaxf(fabsf(p.x + b0), fabsf(p.y + b1));
        const float m1 = fmaxf(fabsf(p.z + b0), fabsf(p.w + b1));
        // m >= 0 always (max over a and -a), so (int) == trunc and
        // ((vi+128) % 256) - 128 == ((vi+128) & 255) - 128.
        float2 r;
        r.x = (float)((((int)m0 + 128) & 255) - 128);
        r.y = (float)((((int)m1 + 128) & 255) - 128);
        out2[i] = r;
    }
}

extern "C" void kernel_launch(void* const* d_in, const int* in_sizes, int n_in,
                              void* d_out, int out_size, void* d_ws, size_t ws_size,
                              hipStream_t stream) {
    const float4* x4     = (const float4*)d_in[0];   // [B,2] f32 -> B/2 float4
    const float*  biases = (const float*)d_in[1];    // [2]
    // d_in[2] (weights) and d_in[3] (threshold) are unused by the reference.
    float2* out2 = (float2*)d_out;

    const int n = out_size / 2;  // B/2 = 4194304 float4 inputs / float2 outputs
    const int block = 256;
    int grid = (n + block - 1) / block;
    if (grid > 2048) grid = 2048;  // grid-stride (8 iters/thread); 256 CU x 8 wg/CU

    morph_kernel<<<grid, block, 0, stream>>>(x4, biases, out2, n);
}